// Round 1
// baseline (380.506 us; speedup 1.0000x reference)
//
#include <hip/hip_runtime.h>
#include <hip/hip_bf16.h>

typedef unsigned short u16;
typedef unsigned int u32;
typedef __attribute__((ext_vector_type(8))) short short8_v;   // 8 bf16 (4 VGPRs), per guide §3
typedef __attribute__((ext_vector_type(4))) float float4_v;

__device__ __forceinline__ u16 f2bf(float f) {
  u32 u = __float_as_uint(f);
  return (u16)((u + 0x7fffu + ((u >> 16) & 1u)) >> 16);   // RNE
}

__device__ __forceinline__ void gl_lds16(const void* g, void* l) {
  __builtin_amdgcn_global_load_lds(
      (const __attribute__((address_space(1))) u32*)g,
      (__attribute__((address_space(3))) u32*)l, 16, 0, 0);
}

// ---------------- gate: MLP -> softmax -> top1 + balance loss ----------------
__global__ void gate_kernel(const float* __restrict__ meta,
                            const float* __restrict__ gw1, const float* __restrict__ gb1,
                            const float* __restrict__ gw2, const float* __restrict__ gb2,
                            int* __restrict__ top1, float* __restrict__ loss_out) {
  const int tid = threadIdx.x;  // 128
  __shared__ float logits[16][6];
  __shared__ float red[2][6];
  __shared__ float probs[16][6];
  float w2c[6];
  #pragma unroll
  for (int k = 0; k < 6; ++k) w2c[k] = gw2[tid * 6 + k];
  const float b1v = gb1[tid];
  for (int b = 0; b < 16; ++b) {
    float h = b1v;
    #pragma unroll
    for (int i = 0; i < 9; ++i) h += meta[b * 9 + i] * gw1[i * 128 + tid];
    h = fmaxf(h, 0.f);
    float v[6];
    #pragma unroll
    for (int k = 0; k < 6; ++k) v[k] = h * w2c[k];
    #pragma unroll
    for (int off = 32; off >= 1; off >>= 1)
      #pragma unroll
      for (int k = 0; k < 6; ++k) v[k] += __shfl_down(v[k], off, 64);
    if ((tid & 63) == 0)
      for (int k = 0; k < 6; ++k) red[tid >> 6][k] = v[k];
    __syncthreads();
    if (tid < 6) logits[b][tid] = red[0][tid] + red[1][tid] + gb2[tid];
    __syncthreads();
  }
  if (tid < 16) {
    const int b = tid;
    float m = logits[b][0];
    for (int k = 1; k < 6; ++k) m = fmaxf(m, logits[b][k]);
    float s = 0.f, p[6];
    for (int k = 0; k < 6; ++k) { p[k] = expf(logits[b][k] - m); s += p[k]; }
    int best = 0; float bm = p[0];
    for (int k = 1; k < 6; ++k) if (p[k] > bm) { bm = p[k]; best = k; }
    top1[b] = best;
    for (int k = 0; k < 6; ++k) probs[b][k] = p[k] / s;
  }
  __syncthreads();
  if (tid == 0) {
    float col[6] = {0, 0, 0, 0, 0, 0}, tot = 0.f;
    for (int b = 0; b < 16; ++b)
      for (int k = 0; k < 6; ++k) col[k] += probs[b][k];
    for (int k = 0; k < 6; ++k) tot += col[k];
    float imp[6], mean = 0.f;
    for (int k = 0; k < 6; ++k) { imp[k] = col[k] / (tot + 1e-8f); mean += imp[k]; }
    mean *= (1.f / 6.f);
    float var = 0.f;
    for (int k = 0; k < 6; ++k) { float d = imp[k] - mean; var += d * d; }
    loss_out[0] = sqrtf(var * 0.2f);   // ddof=1 -> /5
  }
}

// ---------------- fold bias+BN into (scale, shift) per expert channel ----------------
__global__ void fold_kernel(const float* c1b, const float* g1, const float* be1, const float* m1, const float* v1,
                            const float* c2b, const float* g2, const float* be2, const float* m2, const float* v2,
                            float* fold1, float* fold2) {
  int t = blockIdx.x * 256 + threadIdx.x;
  if (t >= 3072) return;
  int conv = t / 1536, r = t % 1536;   // r = e*256 + ch
  if (conv == 0) {
    float scale = g1[r] * rsqrtf(v1[r] + 1e-5f);
    float shift = (c1b[r] - m1[r]) * scale + be1[r];
    fold1[r * 2] = scale; fold1[r * 2 + 1] = shift;
  } else {
    float scale = g2[r] * rsqrtf(v2[r] + 1e-5f);
    float shift = (c2b[r] - m2[r]) * scale + be2[r];
    fold2[r * 2] = scale; fold2[r * 2 + 1] = shift;
  }
}

// ---------------- weights: [E][co][ci][3][3] f32 -> [E][tap][co][ci] bf16 ----------------
__global__ void wprep_kernel(const float* __restrict__ w1, const float* __restrict__ w2,
                             u16* __restrict__ w1t, u16* __restrict__ w2t) {
  int t = blockIdx.x * 256 + threadIdx.x;
  const int PER = 442368;   // 6*9*256*32
  if (t >= 2 * PER) return;
  const float* wsrc; u16* wdst; int r;
  if (t < PER) { wsrc = w1; wdst = w1t; r = t; }
  else         { wsrc = w2; wdst = w2t; r = t - PER; }
  int e = r / 73728;
  int rem = r % 73728;
  int tap = rem / 8192;
  int rem2 = rem % 8192;
  int co = rem2 >> 5;
  int ci0 = (rem2 & 31) * 8;
  const float* sp = wsrc + (((size_t)e * 256 + co) * 256 + ci0) * 9 + tap;
  u16 v[8];
  #pragma unroll
  for (int j = 0; j < 8; ++j) v[j] = f2bf(sp[j * 9]);
  u32 p0 = v[0] | ((u32)v[1] << 16);
  u32 p1 = v[2] | ((u32)v[3] << 16);
  u32 p2 = v[4] | ((u32)v[5] << 16);
  u32 p3 = v[6] | ((u32)v[7] << 16);
  int4 pk = {(int)p0, (int)p1, (int)p2, (int)p3};
  *(int4*)(wdst + (((size_t)e * 9 + tap) * 256 + co) * 256 + ci0) = pk;
}

// ---------------- input: NCHW f32 -> padded [b][rc=66*66][ci=256] bf16 (interior) ----------------
__global__ void transpose_pad_kernel(const float* __restrict__ x, u16* __restrict__ xpt) {
  const int b = blockIdx.x >> 6, r = blockIdx.x & 63;
  const int tid = threadIdx.x;   // 256
  __shared__ u16 tile[64 * 258];
  const int ci_sub = tid >> 6, c = tid & 63;
  const float* xb = x + ((size_t)b * 256) * 4096 + r * 64 + c;
  for (int k = 0; k < 64; ++k) {
    int ci = k * 4 + ci_sub;
    tile[c * 258 + ci] = f2bf(xb[(size_t)ci * 4096]);
  }
  __syncthreads();
  u16* dstb = xpt + ((size_t)b * 4356 + (size_t)(r + 1) * 66 + 1) * 256;
  #pragma unroll
  for (int it = 0; it < 8; ++it) {
    int chunk = it * 256 + tid;
    int cc = chunk >> 5, part = chunk & 31;
    const u32* lp = (const u32*)(tile + cc * 258 + part * 8);
    int4 vv = {(int)lp[0], (int)lp[1], (int)lp[2], (int)lp[3]};
    *(int4*)(dstb + (size_t)cc * 256 + part * 8) = vv;
  }
}

// ---------------- zero padded borders of xpt and hpt ----------------
__global__ void border_zero_kernel(u16* xpt, u16* hpt) {
  int t = blockIdx.x * 256 + threadIdx.x;
  const int TOT = 2 * 16 * 260 * 32;
  if (t >= TOT) return;
  int buf = t / (16 * 260 * 32);
  int r = t % (16 * 260 * 32);
  int b = r / (260 * 32);
  int r2 = r % (260 * 32);
  int idx = r2 >> 5, part = r2 & 31;
  int rc;
  if (idx < 66) rc = idx;                                   // row 0
  else if (idx < 132) rc = 65 * 66 + (idx - 66);            // row 65
  else { int rem = idx - 132; rc = (1 + (rem >> 1)) * 66 + (rem & 1) * 65; }  // cols 0/65
  u16* base = buf ? hpt : xpt;
  int4 z = {0, 0, 0, 0};
  *(int4*)(base + ((size_t)b * 4356 + rc) * 256 + part * 8) = z;
}

// ---------------- conv3x3 + BN + ReLU as implicit GEMM (MFMA bf16) ----------------
// src: [16][4356][256] bf16 padded-transposed. wt: [6][9][256co][256ci] bf16.
// MODE 1: write hidden back in src layout (interior). MODE 2: write f32 NCHW to outF.
// Tile: 128 co x 128 pix (2 image rows), 4 waves (2x2), K-loop = 8 ci-chunks x 9 taps.
// MFMA 16x16x32 frag layouts (guide §3, m89/m91-verified convention):
//   A lane l: A[row=l&15][k=(l>>4)*8+j]; B lane l: B[k=(l>>4)*8+j][col=l&15]
//   D lane l: D[row=(l>>4)*4+reg][col=l&15]
// LDS 16B-slot swizzle: slot = q ^ ((row>>1)&3), applied inverse at the global
// source of global_load_lds (linear LDS dest) and at ds_read (rule #21).
template <int MODE>
__global__ __launch_bounds__(256, 2) void conv_mfma_kernel(
    const u16* __restrict__ src, const u16* __restrict__ wt,
    const int* __restrict__ top1, const float* __restrict__ fold,
    float* __restrict__ outF, u16* __restrict__ outH) {
  __shared__ char Ab[8192];     // [128 co][32 ci]
  __shared__ char Bb[17408];    // [272 rc][32 ci]
  const int tid = threadIdx.x;
  const int lane = tid & 63;
  const int wid = tid >> 6;
  const int wr = wid >> 1, wc = wid & 1;
  const int ptile = blockIdx.x, cot = blockIdx.y, b = blockIdx.z;
  const int e = top1[b];

  const char* srcB0 = (const char*)src + ((size_t)b * 4356 + (size_t)ptile * 132) * 512;
  const char* wA0 = (const char*)wt + ((size_t)e * 9 * 65536 + (size_t)cot * 32768) * 2;

  float4_v acc[4][4];
  #pragma unroll
  for (int m = 0; m < 4; ++m)
    #pragma unroll
    for (int n = 0; n < 4; ++n)
      acc[m][n] = (float4_v){0.f, 0.f, 0.f, 0.f};

  for (int chunk = 0; chunk < 8; ++chunk) {
    #pragma unroll
    for (int tap = 0; tap < 9; ++tap) {
      __syncthreads();   // previous step's frag reads done before overwrite
      if (tap == 0) {
        // stage B: 272 rows x 32 ci = 1088 16B units (8 rows over-stage, unused)
        const char* sB = srcB0 + chunk * 64;
        const int u0 = wid * 256;
        #pragma unroll
        for (int i = 0; i < 4; ++i) {
          int u = u0 + i * 64 + lane;
          int du = u >> 2;
          int qs = (u & 3) ^ ((u >> 3) & 3);
          gl_lds16(sB + (size_t)du * 512 + qs * 16, Bb + (size_t)(u0 + i * 64) * 16);
        }
        if (wid == 0) {
          int u = 1024 + lane;
          int du = u >> 2;
          int qs = (u & 3) ^ ((u >> 3) & 3);
          gl_lds16(sB + (size_t)du * 512 + qs * 16, Bb + 1024 * 16);
        }
      }
      {
        // stage A for this tap: 128 co x 32 ci = 512 units
        const char* sA = wA0 + (size_t)tap * 131072 + chunk * 64;
        const int u0 = wid * 128;
        #pragma unroll
        for (int i = 0; i < 2; ++i) {
          int u = u0 + i * 64 + lane;
          int cl = u >> 2;
          int qs = (u & 3) ^ ((u >> 3) & 3);
          gl_lds16(sA + (size_t)cl * 512 + qs * 16, Ab + (size_t)(u0 + i * 64) * 16);
        }
      }
      __syncthreads();   // compiler drains vmcnt before s_barrier -> staged data visible

      const int kh = tap / 3, kw = tap % 3;
      short8_v av[4], bv[4];
      #pragma unroll
      for (int m = 0; m < 4; ++m) {
        int cl = wr * 64 + m * 16 + (lane & 15);
        int slot = (lane >> 4) ^ ((cl >> 1) & 3);
        av[m] = *(const short8_v*)(Ab + cl * 64 + slot * 16);
      }
      #pragma unroll
      for (int n = 0; n < 4; ++n) {
        int pt = wc * 64 + n * 16 + (lane & 15);
        int rc = ((pt >> 6) + kh) * 66 + (pt & 63) + kw;
        int slot = (lane >> 4) ^ ((rc >> 1) & 3);
        bv[n] = *(const short8_v*)(Bb + rc * 64 + slot * 16);
      }
      #pragma unroll
      for (int m = 0; m < 4; ++m)
        #pragma unroll
        for (int n = 0; n < 4; ++n)
          acc[m][n] = __builtin_amdgcn_mfma_f32_16x16x32_bf16(av[m], bv[n], acc[m][n], 0, 0, 0);
    }
  }

  // epilogue: BN(scale,shift) + ReLU
  const float* fe = fold + (size_t)e * 512;
  #pragma unroll
  for (int m = 0; m < 4; ++m) {
    const int cb = cot * 128 + wr * 64 + m * 16 + ((lane >> 4) << 2);  // 4 consecutive co
    float sc0 = fe[(cb + 0) * 2], sh0 = fe[(cb + 0) * 2 + 1];
    float sc1 = fe[(cb + 1) * 2], sh1 = fe[(cb + 1) * 2 + 1];
    float sc2 = fe[(cb + 2) * 2], sh2 = fe[(cb + 2) * 2 + 1];
    float sc3 = fe[(cb + 3) * 2], sh3 = fe[(cb + 3) * 2 + 1];
    #pragma unroll
    for (int n = 0; n < 4; ++n) {
      const int pt = ptile * 128 + wc * 64 + n * 16 + (lane & 15);
      float v0 = fmaxf(acc[m][n][0] * sc0 + sh0, 0.f);
      float v1 = fmaxf(acc[m][n][1] * sc1 + sh1, 0.f);
      float v2 = fmaxf(acc[m][n][2] * sc2 + sh2, 0.f);
      float v3 = fmaxf(acc[m][n][3] * sc3 + sh3, 0.f);
      if (MODE == 1) {
        const size_t rc = (size_t)((pt >> 6) + 1) * 66 + (pt & 63) + 1;
        uint2 pk;
        pk.x = (u32)f2bf(v0) | ((u32)f2bf(v1) << 16);
        pk.y = (u32)f2bf(v2) | ((u32)f2bf(v3) << 16);
        *(uint2*)(outH + ((size_t)b * 4356 + rc) * 256 + cb) = pk;
      } else {
        float* ob = outF + (size_t)b * 1048576;
        ob[(size_t)(cb + 0) * 4096 + pt] = v0;
        ob[(size_t)(cb + 1) * 4096 + pt] = v1;
        ob[(size_t)(cb + 2) * 4096 + pt] = v2;
        ob[(size_t)(cb + 3) * 4096 + pt] = v3;
      }
    }
  }
}

extern "C" void kernel_launch(void* const* d_in, const int* in_sizes, int n_in,
                              void* d_out, int out_size, void* d_ws, size_t ws_size,
                              hipStream_t stream) {
  const float* x    = (const float*)d_in[0];
  const float* meta = (const float*)d_in[1];
  const float* gw1  = (const float*)d_in[2];
  const float* gb1  = (const float*)d_in[3];
  const float* gw2  = (const float*)d_in[4];
  const float* gb2  = (const float*)d_in[5];
  const float* c1w  = (const float*)d_in[6];
  const float* c1b  = (const float*)d_in[7];
  const float* bn1g = (const float*)d_in[8];
  const float* bn1b = (const float*)d_in[9];
  const float* bn1m = (const float*)d_in[10];
  const float* bn1v = (const float*)d_in[11];
  const float* c2w  = (const float*)d_in[12];
  const float* c2b  = (const float*)d_in[13];
  const float* bn2g = (const float*)d_in[14];
  const float* bn2b = (const float*)d_in[15];
  const float* bn2m = (const float*)d_in[16];
  const float* bn2v = (const float*)d_in[17];

  char* ws = (char*)d_ws;
  u16* xpt   = (u16*)(ws);                    // [16][4356][256] bf16 = 35,684,352 B
  u16* hpt   = (u16*)(ws + 35684352);         // same
  u16* w1t   = (u16*)(ws + 71368704);         // [6][9][256][256] bf16 = 7,077,888 B
  u16* w2t   = (u16*)(ws + 78446592);
  float* fold1 = (float*)(ws + 85524480);     // [6][256][2] f32
  float* fold2 = (float*)(ws + 85536768);
  int* top1  = (int*)(ws + 85549056);

  float* outF = (float*)d_out;
  float* loss = outF + 16777216;

  hipLaunchKernelGGL(gate_kernel, dim3(1), dim3(128), 0, stream,
                     meta, gw1, gb1, gw2, gb2, top1, loss);
  hipLaunchKernelGGL(fold_kernel, dim3(12), dim3(256), 0, stream,
                     c1b, bn1g, bn1b, bn1m, bn1v, c2b, bn2g, bn2b, bn2m, bn2v, fold1, fold2);
  hipLaunchKernelGGL(wprep_kernel, dim3(3456), dim3(256), 0, stream, c1w, c2w, w1t, w2t);
  hipLaunchKernelGGL(transpose_pad_kernel, dim3(1024), dim3(256), 0, stream, x, xpt);
  hipLaunchKernelGGL(border_zero_kernel, dim3(1040), dim3(256), 0, stream, xpt, hpt);
  hipLaunchKernelGGL((conv_mfma_kernel<1>), dim3(32, 2, 16), dim3(256), 0, stream,
                     xpt, w1t, top1, fold1, (float*)nullptr, hpt);
  hipLaunchKernelGGL((conv_mfma_kernel<2>), dim3(32, 2, 16), dim3(256), 0, stream,
                     hpt, w2t, top1, fold2, outF, (u16*)nullptr);
}

// Round 6
// 339.779 us; speedup vs baseline: 1.1199x; 1.1199x over previous
//
#include <hip/hip_runtime.h>
#include <hip/hip_bf16.h>

typedef unsigned short u16;
typedef unsigned int u32;
typedef __attribute__((ext_vector_type(8))) short short8_v;   // 8 bf16 (4 VGPRs)
typedef __attribute__((ext_vector_type(4))) float float4_v;

__device__ __forceinline__ u16 f2bf(float f) {
  u32 u = __float_as_uint(f);
  return (u16)((u + 0x7fffu + ((u >> 16) & 1u)) >> 16);   // RNE
}

__device__ __forceinline__ void gl_lds16(const void* g, void* l) {
  __builtin_amdgcn_global_load_lds(
      (const __attribute__((address_space(1))) u32*)g,
      (__attribute__((address_space(3))) u32*)l, 16, 0, 0);
}

// ---------------- gate: MLP -> softmax -> top1 + balance loss ----------------
__global__ void gate_kernel(const float* __restrict__ meta,
                            const float* __restrict__ gw1, const float* __restrict__ gb1,
                            const float* __restrict__ gw2, const float* __restrict__ gb2,
                            int* __restrict__ top1, float* __restrict__ loss_out) {
  const int tid = threadIdx.x;  // 128
  __shared__ float logits[16][6];
  __shared__ float red[2][6];
  __shared__ float probs[16][6];
  float w2c[6];
  #pragma unroll
  for (int k = 0; k < 6; ++k) w2c[k] = gw2[tid * 6 + k];
  const float b1v = gb1[tid];
  for (int b = 0; b < 16; ++b) {
    float h = b1v;
    #pragma unroll
    for (int i = 0; i < 9; ++i) h += meta[b * 9 + i] * gw1[i * 128 + tid];
    h = fmaxf(h, 0.f);
    float v[6];
    #pragma unroll
    for (int k = 0; k < 6; ++k) v[k] = h * w2c[k];
    #pragma unroll
    for (int off = 32; off >= 1; off >>= 1)
      #pragma unroll
      for (int k = 0; k < 6; ++k) v[k] += __shfl_down(v[k], off, 64);
    if ((tid & 63) == 0)
      for (int k = 0; k < 6; ++k) red[tid >> 6][k] = v[k];
    __syncthreads();
    if (tid < 6) logits[b][tid] = red[0][tid] + red[1][tid] + gb2[tid];
    __syncthreads();
  }
  if (tid < 16) {
    const int b = tid;
    float m = logits[b][0];
    for (int k = 1; k < 6; ++k) m = fmaxf(m, logits[b][k]);
    float s = 0.f, p[6];
    for (int k = 0; k < 6; ++k) { p[k] = expf(logits[b][k] - m); s += p[k]; }
    int best = 0; float bm = p[0];
    for (int k = 1; k < 6; ++k) if (p[k] > bm) { bm = p[k]; best = k; }
    top1[b] = best;
    for (int k = 0; k < 6; ++k) probs[b][k] = p[k] / s;
  }
  __syncthreads();
  if (tid == 0) {
    float col[6] = {0, 0, 0, 0, 0, 0}, tot = 0.f;
    for (int b = 0; b < 16; ++b)
      for (int k = 0; k < 6; ++k) col[k] += probs[b][k];
    for (int k = 0; k < 6; ++k) tot += col[k];
    float imp[6], mean = 0.f;
    for (int k = 0; k < 6; ++k) { imp[k] = col[k] / (tot + 1e-8f); mean += imp[k]; }
    mean *= (1.f / 6.f);
    float var = 0.f;
    for (int k = 0; k < 6; ++k) { float d = imp[k] - mean; var += d * d; }
    loss_out[0] = sqrtf(var * 0.2f);   // ddof=1 -> /5
  }
}

// ---------------- fold bias+BN into (scale, shift) per expert channel ----------------
__global__ void fold_kernel(const float* c1b, const float* g1, const float* be1, const float* m1, const float* v1,
                            const float* c2b, const float* g2, const float* be2, const float* m2, const float* v2,
                            float* fold1, float* fold2) {
  int t = blockIdx.x * 256 + threadIdx.x;
  if (t >= 3072) return;
  int conv = t / 1536, r = t % 1536;   // r = e*256 + ch
  if (conv == 0) {
    float scale = g1[r] * rsqrtf(v1[r] + 1e-5f);
    float shift = (c1b[r] - m1[r]) * scale + be1[r];
    fold1[r * 2] = scale; fold1[r * 2 + 1] = shift;
  } else {
    float scale = g2[r] * rsqrtf(v2[r] + 1e-5f);
    float shift = (c2b[r] - m2[r]) * scale + be2[r];
    fold2[r * 2] = scale; fold2[r * 2 + 1] = shift;
  }
}

// ---------------- weights: [E][co][ci][3][3] f32 -> [E][tap][co][ci] bf16 ----------------
// LDS-staged: contiguous float4 reads of one (e,co) row (2304 f32), transpose, 16B writes.
__global__ void wprep_kernel(const float* __restrict__ w1, const float* __restrict__ w2,
                             u16* __restrict__ w1t, u16* __restrict__ w2t) {
  const int tid = threadIdx.x;   // 256
  const int conv = blockIdx.x >= 1536 ? 1 : 0;
  const int r = blockIdx.x - (conv ? 1536 : 0);   // e*256 + co
  const int e = r >> 8, co = r & 255;
  const float* src = (conv ? w2 : w1) + (size_t)r * 2304;
  u16* wdst = conv ? w2t : w1t;
  __shared__ float buf[2304];
  const float4* s4 = (const float4*)src;
  for (int k = tid; k < 576; k += 256) ((float4*)buf)[k] = s4[k];
  __syncthreads();
  for (int j = tid; j < 288; j += 256) {
    int tap = j >> 5, ci0 = (j & 31) * 8;
    u16 v[8];
    #pragma unroll
    for (int i = 0; i < 8; ++i) v[i] = f2bf(buf[(ci0 + i) * 9 + tap]);
    int4 pk;
    pk.x = (int)((u32)v[0] | ((u32)v[1] << 16));
    pk.y = (int)((u32)v[2] | ((u32)v[3] << 16));
    pk.z = (int)((u32)v[4] | ((u32)v[5] << 16));
    pk.w = (int)((u32)v[6] | ((u32)v[7] << 16));
    *(int4*)(wdst + (((size_t)e * 9 + tap) * 256 + co) * 256 + ci0) = pk;
  }
}

// ---------------- input: NCHW f32 -> padded [b][rc=66*66][ci=256] bf16 (interior) ----------------
__global__ void transpose_pad_kernel(const float* __restrict__ x, u16* __restrict__ xpt) {
  const int b = blockIdx.x >> 6, r = blockIdx.x & 63;
  const int tid = threadIdx.x;   // 256
  __shared__ u16 tile[64 * 258];
  const int cg = tid & 15, ci_g = tid >> 4;
  const float4* xb4 = (const float4*)(x + ((size_t)b * 256) * 4096 + r * 64);
  #pragma unroll
  for (int k = 0; k < 16; ++k) {
    int ci = k * 16 + ci_g;
    float4 v = xb4[(size_t)ci * 1024 + cg];
    tile[(cg * 4 + 0) * 258 + ci] = f2bf(v.x);
    tile[(cg * 4 + 1) * 258 + ci] = f2bf(v.y);
    tile[(cg * 4 + 2) * 258 + ci] = f2bf(v.z);
    tile[(cg * 4 + 3) * 258 + ci] = f2bf(v.w);
  }
  __syncthreads();
  u16* dstb = xpt + ((size_t)b * 4356 + (size_t)(r + 1) * 66 + 1) * 256;
  #pragma unroll
  for (int it = 0; it < 8; ++it) {
    int chunk = it * 256 + tid;
    int cc = chunk >> 5, part = chunk & 31;
    const u32* lp = (const u32*)(tile + cc * 258 + part * 8);
    int4 vv = {(int)lp[0], (int)lp[1], (int)lp[2], (int)lp[3]};
    *(int4*)(dstb + (size_t)cc * 256 + part * 8) = vv;
  }
}

// ---------------- zero padded borders of xpt and hpt ----------------
__global__ void border_zero_kernel(u16* xpt, u16* hpt) {
  int t = blockIdx.x * 256 + threadIdx.x;
  const int TOT = 2 * 16 * 260 * 32;
  if (t >= TOT) return;
  int buf = t / (16 * 260 * 32);
  int r = t % (16 * 260 * 32);
  int b = r / (260 * 32);
  int r2 = r % (260 * 32);
  int idx = r2 >> 5, part = r2 & 31;
  int rc;
  if (idx < 66) rc = idx;                                   // row 0
  else if (idx < 132) rc = 65 * 66 + (idx - 66);            // row 65
  else { int rem = idx - 132; rc = (1 + (rem >> 1)) * 66 + (rem & 1) * 65; }  // cols 0/65
  u16* base = buf ? hpt : xpt;
  int4 z = {0, 0, 0, 0};
  *(int4*)(base + ((size_t)b * 4356 + rc) * 256 + part * 8) = z;
}

// ---------------- conv3x3 + BN + ReLU as implicit GEMM (MFMA bf16) ----------------
// src: [16][4356][256] bf16 padded-transposed. wt: [6][9][256co][256ci] bf16.
// MODE 1: write hidden back in src layout (interior). MODE 2: write f32 NCHW to outF.
// Tile: 256 co x 128 pix (full M), 4 waves (2x2), wave tile 128co x 64pix, acc[8][4].
// Grid: 512 blocks flat (32 ptile x 16 b), bijective XCD swizzle (512%8==0):
// each XCD serves 2 samples -> <=2 experts' weights (2.4MB) resident in its L2.
// K-loop = 8 ci-chunks x 9 taps; B staged per chunk, A per (chunk,tap); 32 MFMA/wave/step.
// LDS 16B-slot swizzle: slot = q ^ ((row>>1)&3), applied inverse at the global
// source of global_load_lds (linear LDS dest) and at ds_read (rule #21).
template <int MODE>
__global__ __launch_bounds__(256, 2) void conv_mfma_kernel(
    const u16* __restrict__ src, const u16* __restrict__ wt,
    const int* __restrict__ top1, const float* __restrict__ fold,
    float* __restrict__ outF, u16* __restrict__ outH) {
  __shared__ char Ab[16384];    // [256 co][32 ci]
  __shared__ char Bb[17408];    // [272 rc][32 ci]
  const int tid = threadIdx.x;
  const int lane = tid & 63;
  const int wid = tid >> 6;
  const int wr = wid >> 1, wc = wid & 1;
  // bijective XCD swizzle: orig%8 = XCD -> give each XCD a contiguous 64-block chunk
  const int orig = blockIdx.x;
  const int swz = (orig & 7) * 64 + (orig >> 3);
  const int ptile = swz & 31, b = swz >> 5;
  const int e = top1[b];

  const char* srcB0 = (const char*)src + ((size_t)b * 4356 + (size_t)ptile * 132) * 512;
  const char* wA0 = (const char*)wt + (size_t)e * 9 * 65536 * 2;

  float4_v acc[8][4];
  #pragma unroll
  for (int m = 0; m < 8; ++m)
    #pragma unroll
    for (int n = 0; n < 4; ++n)
      acc[m][n] = (float4_v){0.f, 0.f, 0.f, 0.f};

  for (int chunk = 0; chunk < 8; ++chunk) {
    #pragma unroll
    for (int tap = 0; tap < 9; ++tap) {
      __syncthreads();   // previous step's frag reads done before overwrite
      if (tap == 0) {
        // stage B: 272 rows x 32 ci = 1088 16B units (8 rows over-stage, unused)
        const char* sB = srcB0 + chunk * 64;
        const int u0 = wid * 256;
        #pragma unroll
        for (int i = 0; i < 4; ++i) {
          int u = u0 + i * 64 + lane;
          int du = u >> 2;
          int qs = (u & 3) ^ ((u >> 3) & 3);
          gl_lds16(sB + (size_t)du * 512 + qs * 16, Bb + (size_t)(u0 + i * 64) * 16);
        }
        if (wid == 0) {
          int u = 1024 + lane;
          int du = u >> 2;
          int qs = (u & 3) ^ ((u >> 3) & 3);
          gl_lds16(sB + (size_t)du * 512 + qs * 16, Bb + 1024 * 16);
        }
      }
      {
        // stage A for this tap: 256 co x 32 ci = 1024 units, 4 per thread
        const char* sA = wA0 + (size_t)tap * 131072 + chunk * 64;
        const int u0 = wid * 256;
        #pragma unroll
        for (int i = 0; i < 4; ++i) {
          int u = u0 + i * 64 + lane;
          int cl = u >> 2;
          int qs = (u & 3) ^ ((u >> 3) & 3);
          gl_lds16(sA + (size_t)cl * 512 + qs * 16, Ab + (size_t)(u0 + i * 64) * 16);
        }
      }
      __syncthreads();   // compiler drains vmcnt before s_barrier -> staged data visible

      const int kh = tap / 3, kw = tap % 3;
      short8_v bv[4];
      #pragma unroll
      for (int n = 0; n < 4; ++n) {
        int pt = wc * 64 + n * 16 + (lane & 15);
        int rc = ((pt >> 6) + kh) * 66 + (pt & 63) + kw;
        int slot = (lane >> 4) ^ ((rc >> 1) & 3);
        bv[n] = *(const short8_v*)(Bb + rc * 64 + slot * 16);
      }
      #pragma unroll
      for (int m = 0; m < 8; ++m) {
        int cl = wr * 128 + m * 16 + (lane & 15);
        int slot = (lane >> 4) ^ ((cl >> 1) & 3);
        short8_v avm = *(const short8_v*)(Ab + cl * 64 + slot * 16);
        #pragma unroll
        for (int n = 0; n < 4; ++n)
          acc[m][n] = __builtin_amdgcn_mfma_f32_16x16x32_bf16(avm, bv[n], acc[m][n], 0, 0, 0);
      }
    }
  }

  // epilogue: BN(scale,shift) + ReLU
  const float* fe = fold + (size_t)e * 512;
  #pragma unroll
  for (int m = 0; m < 8; ++m) {
    const int cb = wr * 128 + m * 16 + ((lane >> 4) << 2);  // 4 consecutive co
    float sc0 = fe[(cb + 0) * 2], sh0 = fe[(cb + 0) * 2 + 1];
    float sc1 = fe[(cb + 1) * 2], sh1 = fe[(cb + 1) * 2 + 1];
    float sc2 = fe[(cb + 2) * 2], sh2 = fe[(cb + 2) * 2 + 1];
    float sc3 = fe[(cb + 3) * 2], sh3 = fe[(cb + 3) * 2 + 1];
    #pragma unroll
    for (int n = 0; n < 4; ++n) {
      const int pt = ptile * 128 + wc * 64 + n * 16 + (lane & 15);
      float v0 = fmaxf(acc[m][n][0] * sc0 + sh0, 0.f);
      float v1 = fmaxf(acc[m][n][1] * sc1 + sh1, 0.f);
      float v2 = fmaxf(acc[m][n][2] * sc2 + sh2, 0.f);
      float v3 = fmaxf(acc[m][n][3] * sc3 + sh3, 0.f);
      if (MODE == 1) {
        const size_t rc = (size_t)((pt >> 6) + 1) * 66 + (pt & 63) + 1;
        uint2 pk;
        pk.x = (u32)f2bf(v0) | ((u32)f2bf(v1) << 16);
        pk.y = (u32)f2bf(v2) | ((u32)f2bf(v3) << 16);
        *(uint2*)(outH + ((size_t)b * 4356 + rc) * 256 + cb) = pk;
      } else {
        float* ob = outF + (size_t)b * 1048576;
        ob[(size_t)(cb + 0) * 4096 + pt] = v0;
        ob[(size_t)(cb + 1) * 4096 + pt] = v1;
        ob[(size_t)(cb + 2) * 4096 + pt] = v2;
        ob[(size_t)(cb + 3) * 4096 + pt] = v3;
      }
    }
  }
}

extern "C" void kernel_launch(void* const* d_in, const int* in_sizes, int n_in,
                              void* d_out, int out_size, void* d_ws, size_t ws_size,
                              hipStream_t stream) {
  const float* x    = (const float*)d_in[0];
  const float* meta = (const float*)d_in[1];
  const float* gw1  = (const float*)d_in[2];
  const float* gb1  = (const float*)d_in[3];
  const float* gw2  = (const float*)d_in[4];
  const float* gb2  = (const float*)d_in[5];
  const float* c1w  = (const float*)d_in[6];
  const float* c1b  = (const float*)d_in[7];
  const float* bn1g = (const float*)d_in[8];
  const float* bn1b = (const float*)d_in[9];
  const float* bn1m = (const float*)d_in[10];
  const float* bn1v = (const float*)d_in[11];
  const float* c2w  = (const float*)d_in[12];
  const float* c2b  = (const float*)d_in[13];
  const float* bn2g = (const float*)d_in[14];
  const float* bn2b = (const float*)d_in[15];
  const float* bn2m = (const float*)d_in[16];
  const float* bn2v = (const float*)d_in[17];

  char* ws = (char*)d_ws;
  u16* xpt   = (u16*)(ws);                    // [16][4356][256] bf16 = 35,684,352 B
  u16* hpt   = (u16*)(ws + 35684352);         // same
  u16* w1t   = (u16*)(ws + 71368704);         // [6][9][256][256] bf16 = 7,077,888 B
  u16* w2t   = (u16*)(ws + 78446592);
  float* fold1 = (float*)(ws + 85524480);     // [6][256][2] f32
  float* fold2 = (float*)(ws + 85536768);
  int* top1  = (int*)(ws + 85549056);

  float* outF = (float*)d_out;
  float* loss = outF + 16777216;

  hipLaunchKernelGGL(gate_kernel, dim3(1), dim3(128), 0, stream,
                     meta, gw1, gb1, gw2, gb2, top1, loss);
  hipLaunchKernelGGL(fold_kernel, dim3(12), dim3(256), 0, stream,
                     c1b, bn1g, bn1b, bn1m, bn1v, c2b, bn2g, bn2b, bn2m, bn2v, fold1, fold2);
  hipLaunchKernelGGL(wprep_kernel, dim3(3072), dim3(256), 0, stream, c1w, c2w, w1t, w2t);
  hipLaunchKernelGGL(transpose_pad_kernel, dim3(1024), dim3(256), 0, stream, x, xpt);
  hipLaunchKernelGGL(border_zero_kernel, dim3(1040), dim3(256), 0, stream, xpt, hpt);
  hipLaunchKernelGGL((conv_mfma_kernel<1>), dim3(512), dim3(256), 0, stream,
                     xpt, w1t, top1, fold1, (float*)nullptr, hpt);
  hipLaunchKernelGGL((conv_mfma_kernel<2>), dim3(512), dim3(256), 0, stream,
                     hpt, w2t, top1, fold2, outF, (u16*)nullptr);
}